// Round 13
// baseline (1422.444 us; speedup 1.0000x reference)
//
#include <hip/hip_runtime.h>
#include <cstdint>
#include <cstddef>
#include <math.h>

#define NEG_SLOPE 0.2f

typedef unsigned short ushort_t;
typedef __attribute__((ext_vector_type(8))) short short8;      // bf16x8 MFMA operand
typedef __attribute__((ext_vector_type(4))) float f32x4;       // MFMA accumulator
typedef _Float16 half8 __attribute__((ext_vector_type(8)));    // fp16x8 row chunk
typedef _Float16 half2_t __attribute__((ext_vector_type(2)));  // fp16x2 packed

// f32 -> bf16 (RNE); bf16 -> f32 is shl 16.
__device__ __forceinline__ ushort_t f2bf(float f) {
    unsigned u = __float_as_uint(f);
    unsigned r = u + 0x7FFFu + ((u >> 16) & 1u);
    return (ushort_t)(r >> 16);
}
__device__ __forceinline__ float bf2f(ushort_t h) {
    return __uint_as_float(((unsigned)h) << 16);
}
__device__ __forceinline__ ushort_t f2h(float f) {
    _Float16 h = (_Float16)f;
    return *(ushort_t*)&h;
}

__device__ __forceinline__ float dot2acc(half2_t a, half2_t b, float c) {
#if __has_builtin(__builtin_amdgcn_fdot2)
    return __builtin_amdgcn_fdot2(a, b, c, false);
#else
    return c + (float)a[0] * (float)b[0] + (float)a[1] * (float)b[1];
#endif
}

// ---------------- edge list with self-loops + degree histogram ----------------
__global__ void build_edges_hist(const int* __restrict__ ei, int E, int N,
                                 int* __restrict__ src, int* __restrict__ dst,
                                 int* __restrict__ deg) {
    int e = blockIdx.x * blockDim.x + threadIdx.x;
    int Et = E + N;
    if (e >= Et) return;
    int s, d;
    if (e < E) { s = ei[e]; d = ei[E + e]; }
    else       { s = d = e - E; }
    src[e] = s;
    dst[e] = d;
    atomicAdd(&deg[d], 1);
}

__global__ void scan1(const int* __restrict__ deg, int N,
                      int* __restrict__ excl, int* __restrict__ partials) {
    __shared__ int tmp[256];
    int i = blockIdx.x * 256 + threadIdx.x;
    int v = (i < N) ? deg[i] : 0;
    tmp[threadIdx.x] = v;
    __syncthreads();
    for (int o = 1; o < 256; o <<= 1) {
        int t = (threadIdx.x >= (unsigned)o) ? tmp[threadIdx.x - o] : 0;
        __syncthreads();
        tmp[threadIdx.x] += t;
        __syncthreads();
    }
    if (i < N) excl[i] = tmp[threadIdx.x] - v;
    if (threadIdx.x == 255) partials[blockIdx.x] = tmp[255];
}

// rowptr[n] final (adds block offset); rowptr[N] = Et; cursor init.
__global__ void scan23(int* __restrict__ rowptr, const int* __restrict__ partials,
                       int nb, int N, int Et, int* __restrict__ cursor) {
    __shared__ int tmp[256];
    int t = threadIdx.x;
    tmp[t] = (t < nb) ? partials[t] : 0;
    __syncthreads();
    for (int o = 1; o < 256; o <<= 1) {
        int x = (t >= o) ? tmp[t - o] : 0;
        __syncthreads();
        tmp[t] += x;
        __syncthreads();
    }
    int off = (blockIdx.x > 0) ? tmp[blockIdx.x - 1] : 0;
    int i = blockIdx.x * 256 + t;
    if (i < N) {
        int v = rowptr[i] + off;
        rowptr[i] = v;
        cursor[i] = v;
    }
    if (blockIdx.x == 0 && t == 0) rowptr[N] = Et;
}

__global__ void scatter_csr(const int* __restrict__ src, const int* __restrict__ dst,
                            int Et, int* __restrict__ cursor, int* __restrict__ csr_src) {
    int e = blockIdx.x * blockDim.x + threadIdx.x;
    if (e >= Et) return;
    int pos = atomicAdd(&cursor[dst[e]], 1);
    csr_src[pos] = src[e];
}

// ---------------- split-bf16 MFMA GEMM ----------------
// out_virtual[N x 2*MOUT] = A[N x 128] @ [Wl | Wr].
// A@W ~= Ah@Wh + Ah@Wlo + Al@Wh  (lo*lo dropped, ~2^-18 relative).
// Both output tables written as fp16 (attention reads them).
template<int MOUT, bool CONVA>
__global__ __launch_bounds__(256) void gemm_mfma(const ushort_t* __restrict__ Ah,
                                                 const ushort_t* __restrict__ Al,
                                                 const float* __restrict__ Af,
                                                 const float* __restrict__ Wl,
                                                 const float* __restrict__ Wr,
                                                 ushort_t* __restrict__ xlh,
                                                 ushort_t* __restrict__ xrh, int N) {
    __shared__ __align__(16) ushort_t Bh[8192];   // 16 KB
    __shared__ __align__(16) ushort_t Bl[8192];   // 16 KB
    const int tid   = threadIdx.x;
    const int row0  = blockIdx.x * 128;
    const int col0v = blockIdx.y * 64;
    const bool isR  = col0v >= MOUT;
    const float* W  = isR ? Wr : Wl;
    const int wcol0 = isR ? (col0v - MOUT) : col0v;
    ushort_t* OUT   = isR ? xrh : xlh;

    #pragma unroll
    for (int i = 0; i < 8; ++i) {
        int idx = tid * 8 + i;
        int k   = idx >> 4;
        int c4  = (idx & 15) * 4;
        float4 w = *(const float4*)(W + (size_t)k * MOUT + wcol0 + c4);
        float wv[4] = {w.x, w.y, w.z, w.w};
        int q = k >> 5, quad = (k >> 3) & 3, j = k & 7;
        #pragma unroll
        for (int e = 0; e < 4; ++e) {
            int c = c4 + e;
            int t = c >> 4;
            int l = (quad << 4) | (c & 15);
            int pos = ((t * 4 + q) * 64 + l) * 8 + j;
            ushort_t hb = f2bf(wv[e]);
            Bh[pos] = hb;
            Bl[pos] = f2bf(wv[e] - bf2f(hb));
        }
    }
    __syncthreads();

    const int wv_  = tid >> 6;
    const int lane = tid & 63;
    const int m    = lane & 15;
    const int quad = lane >> 4;
    const int wrow0 = row0 + wv_ * 32;

    f32x4 acc[2][4] = {};

    for (int q = 0; q < 4; ++q) {
        short8 ahf[2], alf[2];
        #pragma unroll
        for (int r = 0; r < 2; ++r) {
            int row = wrow0 + 16 * r + m;
            row = row < N ? row : N - 1;
            size_t off = (size_t)row * 128 + q * 32 + quad * 8;
            if constexpr (CONVA) {
                float4 f0 = *(const float4*)(Af + off);
                float4 f1 = *(const float4*)(Af + off + 4);
                float fv[8] = {f0.x, f0.y, f0.z, f0.w, f1.x, f1.y, f1.z, f1.w};
                short ah[8], al[8];
                #pragma unroll
                for (int e = 0; e < 8; ++e) {
                    ushort_t hb = f2bf(fv[e]);
                    ah[e] = (short)hb;
                    al[e] = (short)f2bf(fv[e] - bf2f(hb));
                }
                ahf[r] = short8{ah[0],ah[1],ah[2],ah[3],ah[4],ah[5],ah[6],ah[7]};
                alf[r] = short8{al[0],al[1],al[2],al[3],al[4],al[5],al[6],al[7]};
            } else {
                ahf[r] = *(const short8*)(Ah + off);
                alf[r] = *(const short8*)(Al + off);
            }
        }
        #pragma unroll
        for (int t = 0; t < 4; ++t) {
            int base = ((t * 4 + q) * 64 + lane) * 8;
            short8 bh = *(const short8*)(Bh + base);
            short8 bl = *(const short8*)(Bl + base);
            #pragma unroll
            for (int r = 0; r < 2; ++r) {
                acc[r][t] = __builtin_amdgcn_mfma_f32_16x16x32_bf16(ahf[r], bh, acc[r][t], 0, 0, 0);
                acc[r][t] = __builtin_amdgcn_mfma_f32_16x16x32_bf16(ahf[r], bl, acc[r][t], 0, 0, 0);
                acc[r][t] = __builtin_amdgcn_mfma_f32_16x16x32_bf16(alf[r], bh, acc[r][t], 0, 0, 0);
            }
        }
    }

    #pragma unroll
    for (int r = 0; r < 2; ++r)
        #pragma unroll
        for (int i = 0; i < 4; ++i) {
            int row = wrow0 + 16 * r + quad * 4 + i;
            if (row < N) {
                #pragma unroll
                for (int t = 0; t < 4; ++t)
                    OUT[(size_t)row * MOUT + wcol0 + t * 16 + m] = f2h(acc[r][t][i]);
            }
        }
}

// ---------------- fused per-node attention (persistent waves, dynamic pool) ----------------
// Persistent grid (8 blocks/CU x 4 waves); each wave grabs chunks of CH=2
// consecutive nodes from a global cursor (atomicAdd once per chunk; the grab
// for chunk k+1 is issued before processing chunk k so its latency hides).
// No wave idles while nodes remain -> block-level load imbalance and backfill
// stalls (the R12 occupancy ceiling) disappear.  Inner loop unchanged from
// R11/R12: VPT=8 ch/lane, EPW edges concurrently, packed fp16 math, max-free
// softmax, DR=4 gather ring, metadata pipelining, deg>64 fallback.
template<int H, int C, bool ELU, int OMODE>
__global__ __launch_bounds__(256) void node_attn(const ushort_t* __restrict__ xlh,
                                                 const ushort_t* __restrict__ xrh,
                                                 const float* __restrict__ att,
                                                 const float* __restrict__ bias,
                                                 const int* __restrict__ rowptr,
                                                 const int* __restrict__ csr_src,
                                                 int N, int* __restrict__ ctr,
                                                 float* __restrict__ out,
                                                 ushort_t* __restrict__ outh,
                                                 ushort_t* __restrict__ outl) {
    constexpr int HC  = H * C;          // 128 / 64
    constexpr int VPT = 8;
    constexpr int LPE = HC / VPT;       // 16 / 8
    constexpr int EPW = 64 / LPE;       // 4 / 8
    constexpr int GROUP = C / VPT;      // 4 / 8 (lanes per head)
    constexpr int DR  = 4;
    constexpr int CH  = 2;              // nodes per grab

    const int lane = threadIdx.x & 63;
    const int sub = lane & (LPE - 1);
    const int grp = lane / LPE;         // edge slot
    const int ch0 = sub * VPT;

    half2_t a2[4];
    {
        float4 u0 = *(const float4*)(att + ch0);
        float4 u1 = *(const float4*)(att + ch0 + 4);
        a2[0] = half2_t{(_Float16)u0.x, (_Float16)u0.y};
        a2[1] = half2_t{(_Float16)u0.z, (_Float16)u0.w};
        a2[2] = half2_t{(_Float16)u1.x, (_Float16)u1.y};
        a2[3] = half2_t{(_Float16)u1.z, (_Float16)u1.w};
    }
    const half2_t c02 = half2_t{(_Float16)NEG_SLOPE, (_Float16)NEG_SLOPE};

    auto grab = [&]() -> int {
        int b = 0;
        if (lane == 0) b = atomicAdd(ctr, CH);
        return __shfl(b, 0, 64);
    };

    // ---- pipelined per-node metadata ----
    int nj0, ndg, nmyidx;
    half8 nxrv;
    auto loadmeta = [&](int n) {
        int2 rp = *(const int2*)(rowptr + n);        // one 8B load
        nj0 = rp.x;
        ndg = rp.y - rp.x;                           // >= 1 (self-loop)
        nxrv   = *(const half8*)(xrh + (size_t)n * HC + ch0);
        nmyidx = csr_src[nj0 + (lane < ndg ? lane : 0)];
    };

    int base = grab();
    if (base >= N) return;
    loadmeta(base);
    int nextbase = grab();                           // in flight during chunk

    while (true) {
        #pragma unroll
        for (int g = 0; g < CH; ++g) {
            const int n = base + g;
            if (n >= N) break;                       // wave-uniform
            const int j0 = nj0, dg = ndg;
            const int myidx = nmyidx;
            const half8 xrv = nxrv;
            // prefetch next node's metadata chain
            {
                int nn = (g + 1 < CH && n + 1 < N) ? (n + 1) : nextbase;
                if (nn < N && !(g + 1 == CH && nextbase >= N)) loadmeta(nn);
            }

            const int dgf   = dg < 64 ? dg : 64;
            const int iters = (dgf + EPW - 1) / EPW;

            auto bidx = [&](int it) {
                int e = it * EPW + grp;
                e = e < dgf ? e : (dgf - 1);
                return __shfl(myidx, e, 64);
            };
            auto ldrow = [&](int s) -> half8 {
                return *(const half8*)(xlh + (size_t)s * HC + ch0);   // 16 B
            };

            float d = 0.f;
            float acc[VPT] = {};

            auto process = [&](half8 v, bool valid) {
                float p = 0.f;
                #pragma unroll
                for (int i = 0; i < 4; ++i) {
                    half2_t v2 = half2_t{v[2 * i], v[2 * i + 1]};
                    half2_t x2 = half2_t{xrv[2 * i], xrv[2 * i + 1]};
                    half2_t m2 = v2 + x2;                                 // v_pk_add_f16
                    half2_t lr = __builtin_elementwise_max(m2, c02 * m2); // pk_mul+pk_max
                    p = dot2acc(lr, a2[i], p);                            // v_dot2_f32_f16
                }
                #pragma unroll
                for (int o = GROUP >> 1; o > 0; o >>= 1)
                    p += __shfl_xor(p, o, 64);
                float pe = valid ? __expf(p) : 0.f;
                d += pe;
                #pragma unroll
                for (int i = 0; i < VPT; ++i)
                    acc[i] += pe * (float)v[i];                           // fma_mix
            };

            half8 buf[DR];
            #pragma unroll
            for (int k = 0; k < DR; ++k) buf[k] = ldrow(bidx(k));

            int j = 0;
            for (; j + DR <= iters; j += DR) {
                #pragma unroll
                for (int k = 0; k < DR; ++k) {
                    half8 v = buf[k];
                    buf[k] = ldrow(bidx(j + k + DR));
                    process(v, (j + k) * EPW + grp < dgf);
                }
            }
            #pragma unroll
            for (int k = 0; k < DR; ++k)
                if (j + k < iters) process(buf[k], (j + k) * EPW + grp < dgf);

            // rare fallback: edges beyond the first 64 (wave-uniform condition)
            if (dg > 64) {
                for (int e0 = 64; e0 < dg; e0 += EPW) {
                    int e = e0 + grp;
                    bool valid = e < dg;
                    int s = csr_src[j0 + (valid ? e : 0)];
                    process(ldrow(s), valid);
                }
            }

            // merge the EPW concurrent partial sums (shared exp scale)
            #pragma unroll
            for (int off = LPE; off < 64; off <<= 1) {
                d += __shfl_xor(d, off, 64);
                #pragma unroll
                for (int i = 0; i < VPT; ++i)
                    acc[i] += __shfl_xor(acc[i], off, 64);
            }

            if (lane < LPE) {
                float inv = 1.f / d;
                float vv[VPT];
                #pragma unroll
                for (int i = 0; i < VPT; ++i) {
                    float v = acc[i] * inv + bias[ch0 + i];
                    if (ELU) v = v > 0.f ? v : (__expf(v) - 1.f);
                    vv[i] = v;
                }
                if (OMODE == 0) {
                    *(float4*)(out + (size_t)n * HC + ch0) =
                        make_float4(vv[0], vv[1], vv[2], vv[3]);
                    *(float4*)(out + (size_t)n * HC + ch0 + 4) =
                        make_float4(vv[4], vv[5], vv[6], vv[7]);
                } else {
                    ushort_t hb[VPT], lb[VPT];
                    #pragma unroll
                    for (int i = 0; i < VPT; ++i) {
                        hb[i] = f2bf(vv[i]);
                        lb[i] = f2bf(vv[i] - bf2f(hb[i]));
                    }
                    *(ushort4*)(outh + (size_t)n * HC + ch0) =
                        ushort4{hb[0], hb[1], hb[2], hb[3]};
                    *(ushort4*)(outh + (size_t)n * HC + ch0 + 4) =
                        ushort4{hb[4], hb[5], hb[6], hb[7]};
                    *(ushort4*)(outl + (size_t)n * HC + ch0) =
                        ushort4{lb[0], lb[1], lb[2], lb[3]};
                    *(ushort4*)(outl + (size_t)n * HC + ch0 + 4) =
                        ushort4{lb[4], lb[5], lb[6], lb[7]};
                }
            }
        }
        base = nextbase;
        if (base >= N) break;                        // wave-uniform
        nextbase = grab();
    }
}

// ---------------- launch ----------------
extern "C" void kernel_launch(void* const* d_in, const int* in_sizes, int n_in,
                              void* d_out, int out_size, void* d_ws, size_t ws_size,
                              hipStream_t stream) {
    const float* x   = (const float*)d_in[0];
    const int*   ei  = (const int*)d_in[1];
    const float* Wl1 = (const float*)d_in[2];
    const float* Wr1 = (const float*)d_in[3];
    const float* a1  = (const float*)d_in[4];
    const float* b1  = (const float*)d_in[5];
    const float* Wl2 = (const float*)d_in[6];
    const float* Wr2 = (const float*)d_in[7];
    const float* a2  = (const float*)d_in[8];
    const float* b2  = (const float*)d_in[9];
    const float* Wl3 = (const float*)d_in[10];
    const float* Wr3 = (const float*)d_in[11];
    const float* a3  = (const float*)d_in[12];
    const float* b3  = (const float*)d_in[13];

    const int N  = in_sizes[0] / 128;   // 50000
    const int E  = in_sizes[1] / 2;     // 800000
    const int Et = E + N;               // 850000
    const int nb = (N + 255) / 256;

    char* p = (char*)d_ws;
    auto alloc = [&](size_t bytes) -> void* {
        void* r = (void*)p;
        p += (bytes + 255) & ~(size_t)255;
        return r;
    };
    int*      src      = (int*)alloc((size_t)Et * 4);
    int*      dst      = (int*)alloc((size_t)Et * 4);
    int*      csr_src  = (int*)alloc((size_t)Et * 4 + 256);
    int*      deg      = (int*)alloc((size_t)N * 4);
    int*      rowptr   = (int*)alloc((size_t)(N + 1) * 4);
    int*      cursor   = (int*)alloc((size_t)N * 4);
    int*      partials = (int*)alloc((size_t)nb * 4);
    int*      ctrs     = (int*)alloc(3 * 4);                     // dynamic-pool cursors
    ushort_t* xlh      = (ushort_t*)alloc((size_t)N * 128 * 2);  // fp16 gather table
    ushort_t* xrh      = (ushort_t*)alloc((size_t)N * 128 * 2);  // fp16 target table
    ushort_t* Ah       = (ushort_t*)alloc((size_t)N * 128 * 2);
    ushort_t* Al       = (ushort_t*)alloc((size_t)N * 128 * 2);

    const int rowBlocks  = (N + 127) / 128;      // 391
    const int poolBlocks = 2048;                 // 8 blocks/CU x 4 waves, persistent
    const int edgeBlocks = (Et + 255) / 256;

    // ---- CSR by dst (once; reused by all layers) ----
    hipMemsetAsync(deg, 0, (size_t)N * 4, stream);
    hipMemsetAsync(ctrs, 0, 3 * 4, stream);
    build_edges_hist<<<edgeBlocks, 256, 0, stream>>>(ei, E, N, src, dst, deg);
    scan1<<<nb, 256, 0, stream>>>(deg, N, rowptr, partials);
    scan23<<<nb, 256, 0, stream>>>(rowptr, partials, nb, N, Et, cursor);
    scatter_csr<<<edgeBlocks, 256, 0, stream>>>(src, dst, Et, cursor, csr_src);

    // ---- layer 1: 128 -> 4x32, concat, ELU (A converted inline from f32) ----
    gemm_mfma<128, true><<<dim3(rowBlocks, 4), 256, 0, stream>>>(
        nullptr, nullptr, x, Wl1, Wr1, xlh, xrh, N);
    node_attn<4, 32, true, 1><<<poolBlocks, 256, 0, stream>>>(
        xlh, xrh, a1, b1, rowptr, csr_src, N, ctrs + 0, nullptr, Ah, Al);

    // ---- layer 2: 128 -> 4x32, concat, ELU ----
    gemm_mfma<128, false><<<dim3(rowBlocks, 4), 256, 0, stream>>>(
        Ah, Al, nullptr, Wl2, Wr2, xlh, xrh, N);
    node_attn<4, 32, true, 1><<<poolBlocks, 256, 0, stream>>>(
        xlh, xrh, a2, b2, rowptr, csr_src, N, ctrs + 1, nullptr, Ah, Al);

    // ---- layer 3: 128 -> 64, heads=1, concat=False ----
    float* out = (float*)d_out;
    gemm_mfma<64, false><<<dim3(rowBlocks, 2), 256, 0, stream>>>(
        Ah, Al, nullptr, Wl3, Wr3, xlh, xrh, N);
    node_attn<1, 64, false, 0><<<poolBlocks, 256, 0, stream>>>(
        xlh, xrh, a3, b3, rowptr, csr_src, N, ctrs + 2, out, nullptr, nullptr);
}

// Round 14
// 382.211 us; speedup vs baseline: 3.7216x; 3.7216x over previous
//
#include <hip/hip_runtime.h>
#include <cstdint>
#include <cstddef>
#include <math.h>

#define NEG_SLOPE 0.2f

typedef unsigned short ushort_t;
typedef __attribute__((ext_vector_type(8))) short short8;      // bf16x8 MFMA operand
typedef __attribute__((ext_vector_type(4))) float f32x4;       // MFMA accumulator
typedef _Float16 half8 __attribute__((ext_vector_type(8)));    // fp16x8 row chunk
typedef _Float16 half2_t __attribute__((ext_vector_type(2)));  // fp16x2 packed

// f32 -> bf16 (RNE); bf16 -> f32 is shl 16.
__device__ __forceinline__ ushort_t f2bf(float f) {
    unsigned u = __float_as_uint(f);
    unsigned r = u + 0x7FFFu + ((u >> 16) & 1u);
    return (ushort_t)(r >> 16);
}
__device__ __forceinline__ float bf2f(ushort_t h) {
    return __uint_as_float(((unsigned)h) << 16);
}
__device__ __forceinline__ ushort_t f2h(float f) {
    _Float16 h = (_Float16)f;
    return *(ushort_t*)&h;
}

__device__ __forceinline__ float dot2acc(half2_t a, half2_t b, float c) {
#if __has_builtin(__builtin_amdgcn_fdot2)
    return __builtin_amdgcn_fdot2(a, b, c, false);
#else
    return c + (float)a[0] * (float)b[0] + (float)a[1] * (float)b[1];
#endif
}

// ---------------- edge list with self-loops + degree histogram ----------------
__global__ void build_edges_hist(const int* __restrict__ ei, int E, int N,
                                 int* __restrict__ src, int* __restrict__ dst,
                                 int* __restrict__ deg) {
    int e = blockIdx.x * blockDim.x + threadIdx.x;
    int Et = E + N;
    if (e >= Et) return;
    int s, d;
    if (e < E) { s = ei[e]; d = ei[E + e]; }
    else       { s = d = e - E; }
    src[e] = s;
    dst[e] = d;
    atomicAdd(&deg[d], 1);
}

__global__ void scan1(const int* __restrict__ deg, int N,
                      int* __restrict__ excl, int* __restrict__ partials) {
    __shared__ int tmp[256];
    int i = blockIdx.x * 256 + threadIdx.x;
    int v = (i < N) ? deg[i] : 0;
    tmp[threadIdx.x] = v;
    __syncthreads();
    for (int o = 1; o < 256; o <<= 1) {
        int t = (threadIdx.x >= (unsigned)o) ? tmp[threadIdx.x - o] : 0;
        __syncthreads();
        tmp[threadIdx.x] += t;
        __syncthreads();
    }
    if (i < N) excl[i] = tmp[threadIdx.x] - v;
    if (threadIdx.x == 255) partials[blockIdx.x] = tmp[255];
}

__global__ void scan23(int* __restrict__ excl, const int* __restrict__ partials,
                       int nb, int N, int* __restrict__ cursor) {
    __shared__ int tmp[256];
    int t = threadIdx.x;
    tmp[t] = (t < nb) ? partials[t] : 0;
    __syncthreads();
    for (int o = 1; o < 256; o <<= 1) {
        int x = (t >= o) ? tmp[t - o] : 0;
        __syncthreads();
        tmp[t] += x;
        __syncthreads();
    }
    int off = (blockIdx.x > 0) ? tmp[blockIdx.x - 1] : 0;
    int i = blockIdx.x * 256 + t;
    if (i < N) {
        int v = excl[i] + off;
        excl[i] = v;
        cursor[i] = v;
    }
}

__global__ void scatter_csr(const int* __restrict__ src, const int* __restrict__ dst,
                            int Et, int* __restrict__ cursor, int* __restrict__ csr_src) {
    int e = blockIdx.x * blockDim.x + threadIdx.x;
    if (e >= Et) return;
    int pos = atomicAdd(&cursor[dst[e]], 1);
    csr_src[pos] = src[e];
}

// ---------------- split-bf16 MFMA GEMM ----------------
// out_virtual[N x 2*MOUT] = A[N x 128] @ [Wl | Wr].
// A@W ~= Ah@Wh + Ah@Wlo + Al@Wh  (lo*lo dropped, ~2^-18 relative).
// Both output tables written as fp16 (attention reads them).
template<int MOUT, bool CONVA>
__global__ __launch_bounds__(256) void gemm_mfma(const ushort_t* __restrict__ Ah,
                                                 const ushort_t* __restrict__ Al,
                                                 const float* __restrict__ Af,
                                                 const float* __restrict__ Wl,
                                                 const float* __restrict__ Wr,
                                                 ushort_t* __restrict__ xlh,
                                                 ushort_t* __restrict__ xrh, int N) {
    __shared__ __align__(16) ushort_t Bh[8192];   // 16 KB
    __shared__ __align__(16) ushort_t Bl[8192];   // 16 KB
    const int tid   = threadIdx.x;
    const int row0  = blockIdx.x * 128;
    const int col0v = blockIdx.y * 64;
    const bool isR  = col0v >= MOUT;
    const float* W  = isR ? Wr : Wl;
    const int wcol0 = isR ? (col0v - MOUT) : col0v;
    ushort_t* OUT   = isR ? xrh : xlh;

    #pragma unroll
    for (int i = 0; i < 8; ++i) {
        int idx = tid * 8 + i;
        int k   = idx >> 4;
        int c4  = (idx & 15) * 4;
        float4 w = *(const float4*)(W + (size_t)k * MOUT + wcol0 + c4);
        float wv[4] = {w.x, w.y, w.z, w.w};
        int q = k >> 5, quad = (k >> 3) & 3, j = k & 7;
        #pragma unroll
        for (int e = 0; e < 4; ++e) {
            int c = c4 + e;
            int t = c >> 4;
            int l = (quad << 4) | (c & 15);
            int pos = ((t * 4 + q) * 64 + l) * 8 + j;
            ushort_t hb = f2bf(wv[e]);
            Bh[pos] = hb;
            Bl[pos] = f2bf(wv[e] - bf2f(hb));
        }
    }
    __syncthreads();

    const int wv_  = tid >> 6;
    const int lane = tid & 63;
    const int m    = lane & 15;
    const int quad = lane >> 4;
    const int wrow0 = row0 + wv_ * 32;

    f32x4 acc[2][4] = {};

    for (int q = 0; q < 4; ++q) {
        short8 ahf[2], alf[2];
        #pragma unroll
        for (int r = 0; r < 2; ++r) {
            int row = wrow0 + 16 * r + m;
            row = row < N ? row : N - 1;
            size_t off = (size_t)row * 128 + q * 32 + quad * 8;
            if constexpr (CONVA) {
                float4 f0 = *(const float4*)(Af + off);
                float4 f1 = *(const float4*)(Af + off + 4);
                float fv[8] = {f0.x, f0.y, f0.z, f0.w, f1.x, f1.y, f1.z, f1.w};
                short ah[8], al[8];
                #pragma unroll
                for (int e = 0; e < 8; ++e) {
                    ushort_t hb = f2bf(fv[e]);
                    ah[e] = (short)hb;
                    al[e] = (short)f2bf(fv[e] - bf2f(hb));
                }
                ahf[r] = short8{ah[0],ah[1],ah[2],ah[3],ah[4],ah[5],ah[6],ah[7]};
                alf[r] = short8{al[0],al[1],al[2],al[3],al[4],al[5],al[6],al[7]};
            } else {
                ahf[r] = *(const short8*)(Ah + off);
                alf[r] = *(const short8*)(Al + off);
            }
        }
        #pragma unroll
        for (int t = 0; t < 4; ++t) {
            int base = ((t * 4 + q) * 64 + lane) * 8;
            short8 bh = *(const short8*)(Bh + base);
            short8 bl = *(const short8*)(Bl + base);
            #pragma unroll
            for (int r = 0; r < 2; ++r) {
                acc[r][t] = __builtin_amdgcn_mfma_f32_16x16x32_bf16(ahf[r], bh, acc[r][t], 0, 0, 0);
                acc[r][t] = __builtin_amdgcn_mfma_f32_16x16x32_bf16(ahf[r], bl, acc[r][t], 0, 0, 0);
                acc[r][t] = __builtin_amdgcn_mfma_f32_16x16x32_bf16(alf[r], bh, acc[r][t], 0, 0, 0);
            }
        }
    }

    #pragma unroll
    for (int r = 0; r < 2; ++r)
        #pragma unroll
        for (int i = 0; i < 4; ++i) {
            int row = wrow0 + 16 * r + quad * 4 + i;
            if (row < N) {
                #pragma unroll
                for (int t = 0; t < 4; ++t)
                    OUT[(size_t)row * MOUT + wcol0 + t * 16 + m] = f2h(acc[r][t][i]);
            }
        }
}

// ---------------- fused per-node attention (fp16 gather + packed math) ----------------
// R11 structure (the best measured): one wave per node, static mapping.
// Changes vs R11: 128-thread blocks (2 waves — finer backfill granularity) and
// DR=6 gather ring (6 outstanding row loads/wave -> more per-CU MLP toward the
// 10 B/cyc/CU load-return ceiling).  VPT=8 ch/lane; EPW edges concurrently
// (wide 4 / L3 8); packed fp16 math; max-free softmax; indices coalesced once
// + shfl broadcast; deg>64 wave-uniform fallback.
template<int H, int C, bool ELU, int OMODE>
__global__ __launch_bounds__(128) void node_attn(const ushort_t* __restrict__ xlh,
                                                 const ushort_t* __restrict__ xrh,
                                                 const float* __restrict__ att,
                                                 const float* __restrict__ bias,
                                                 const int* __restrict__ rowstart,
                                                 const int* __restrict__ deg,
                                                 const int* __restrict__ csr_src,
                                                 int N, float* __restrict__ out,
                                                 ushort_t* __restrict__ outh,
                                                 ushort_t* __restrict__ outl) {
    constexpr int HC  = H * C;          // 128 / 64
    constexpr int VPT = 8;
    constexpr int LPE = HC / VPT;       // 16 / 8
    constexpr int EPW = 64 / LPE;       // 4 / 8
    constexpr int GROUP = C / VPT;      // 4 / 8 (lanes per head)
    constexpr int DR  = 6;

    int wid  = blockIdx.x * 2 + (threadIdx.x >> 6);
    int lane = threadIdx.x & 63;
    if (wid >= N) return;
    const int n   = wid;
    const int sub = lane & (LPE - 1);
    const int grp = lane / LPE;         // edge slot
    const int ch0 = sub * VPT;

    half8 xrv = *(const half8*)(xrh + (size_t)n * HC + ch0);
    half2_t a2[4];
    {
        float4 u0 = *(const float4*)(att + ch0);
        float4 u1 = *(const float4*)(att + ch0 + 4);
        a2[0] = half2_t{(_Float16)u0.x, (_Float16)u0.y};
        a2[1] = half2_t{(_Float16)u0.z, (_Float16)u0.w};
        a2[2] = half2_t{(_Float16)u1.x, (_Float16)u1.y};
        a2[3] = half2_t{(_Float16)u1.z, (_Float16)u1.w};
    }
    const half2_t c02 = half2_t{(_Float16)NEG_SLOPE, (_Float16)NEG_SLOPE};

    const int j0 = rowstart[n];
    const int dg = deg[n];              // >= 1 (self-loop)
    int myidx = csr_src[j0 + (lane < dg ? lane : 0)];

    const int dgf   = dg < 64 ? dg : 64;
    const int iters = (dgf + EPW - 1) / EPW;

    auto bidx = [&](int it) {
        int e = it * EPW + grp;
        e = e < dgf ? e : (dgf - 1);
        return __shfl(myidx, e, 64);
    };
    auto ldrow = [&](int s) -> half8 {
        return *(const half8*)(xlh + (size_t)s * HC + ch0);   // 16 B
    };

    float d = 0.f;
    float acc[VPT] = {};

    auto process = [&](half8 v, bool valid) {
        float p = 0.f;
        #pragma unroll
        for (int i = 0; i < 4; ++i) {
            half2_t v2 = half2_t{v[2 * i], v[2 * i + 1]};
            half2_t x2 = half2_t{xrv[2 * i], xrv[2 * i + 1]};
            half2_t m2 = v2 + x2;                                 // v_pk_add_f16
            half2_t lr = __builtin_elementwise_max(m2, c02 * m2); // pk_mul+pk_max
            p = dot2acc(lr, a2[i], p);                            // v_dot2_f32_f16
        }
        #pragma unroll
        for (int o = GROUP >> 1; o > 0; o >>= 1)
            p += __shfl_xor(p, o, 64);
        float pe = valid ? __expf(p) : 0.f;
        d += pe;
        #pragma unroll
        for (int i = 0; i < VPT; ++i)
            acc[i] += pe * (float)v[i];                           // fma_mix-able
    };

    half8 buf[DR];
    #pragma unroll
    for (int k = 0; k < DR; ++k) buf[k] = ldrow(bidx(k));

    int j = 0;
    for (; j + DR <= iters; j += DR) {
        #pragma unroll
        for (int k = 0; k < DR; ++k) {
            half8 v = buf[k];
            buf[k] = ldrow(bidx(j + k + DR));
            process(v, (j + k) * EPW + grp < dgf);
        }
    }
    #pragma unroll
    for (int k = 0; k < DR; ++k)
        if (j + k < iters) process(buf[k], (j + k) * EPW + grp < dgf);

    // rare fallback: edges beyond the first 64 (wave-uniform condition)
    if (dg > 64) {
        for (int e0 = 64; e0 < dg; e0 += EPW) {
            int e = e0 + grp;
            bool valid = e < dg;
            int s = csr_src[j0 + (valid ? e : 0)];
            process(ldrow(s), valid);
        }
    }

    // merge the EPW concurrent partial sums (shared exp scale)
    #pragma unroll
    for (int off = LPE; off < 64; off <<= 1) {
        d += __shfl_xor(d, off, 64);
        #pragma unroll
        for (int i = 0; i < VPT; ++i)
            acc[i] += __shfl_xor(acc[i], off, 64);
    }

    if (lane < LPE) {
        float inv = 1.f / d;
        float vv[VPT];
        #pragma unroll
        for (int i = 0; i < VPT; ++i) {
            float v = acc[i] * inv + bias[ch0 + i];
            if (ELU) v = v > 0.f ? v : (__expf(v) - 1.f);
            vv[i] = v;
        }
        if (OMODE == 0) {
            *(float4*)(out + (size_t)n * HC + ch0) =
                make_float4(vv[0], vv[1], vv[2], vv[3]);
            *(float4*)(out + (size_t)n * HC + ch0 + 4) =
                make_float4(vv[4], vv[5], vv[6], vv[7]);
        } else {
            ushort_t hb[VPT], lb[VPT];
            #pragma unroll
            for (int i = 0; i < VPT; ++i) {
                hb[i] = f2bf(vv[i]);
                lb[i] = f2bf(vv[i] - bf2f(hb[i]));
            }
            *(ushort4*)(outh + (size_t)n * HC + ch0) =
                ushort4{hb[0], hb[1], hb[2], hb[3]};
            *(ushort4*)(outh + (size_t)n * HC + ch0 + 4) =
                ushort4{hb[4], hb[5], hb[6], hb[7]};
            *(ushort4*)(outl + (size_t)n * HC + ch0) =
                ushort4{lb[0], lb[1], lb[2], lb[3]};
            *(ushort4*)(outl + (size_t)n * HC + ch0 + 4) =
                ushort4{lb[4], lb[5], lb[6], lb[7]};
        }
    }
}

// ---------------- launch ----------------
extern "C" void kernel_launch(void* const* d_in, const int* in_sizes, int n_in,
                              void* d_out, int out_size, void* d_ws, size_t ws_size,
                              hipStream_t stream) {
    const float* x   = (const float*)d_in[0];
    const int*   ei  = (const int*)d_in[1];
    const float* Wl1 = (const float*)d_in[2];
    const float* Wr1 = (const float*)d_in[3];
    const float* a1  = (const float*)d_in[4];
    const float* b1  = (const float*)d_in[5];
    const float* Wl2 = (const float*)d_in[6];
    const float* Wr2 = (const float*)d_in[7];
    const float* a2  = (const float*)d_in[8];
    const float* b2  = (const float*)d_in[9];
    const float* Wl3 = (const float*)d_in[10];
    const float* Wr3 = (const float*)d_in[11];
    const float* a3  = (const float*)d_in[12];
    const float* b3  = (const float*)d_in[13];

    const int N  = in_sizes[0] / 128;   // 50000
    const int E  = in_sizes[1] / 2;     // 800000
    const int Et = E + N;               // 850000
    const int nb = (N + 255) / 256;

    char* p = (char*)d_ws;
    auto alloc = [&](size_t bytes) -> void* {
        void* r = (void*)p;
        p += (bytes + 255) & ~(size_t)255;
        return r;
    };
    int*      src      = (int*)alloc((size_t)Et * 4);
    int*      dst      = (int*)alloc((size_t)Et * 4);
    int*      csr_src  = (int*)alloc((size_t)Et * 4 + 256);
    int*      deg      = (int*)alloc((size_t)N * 4);
    int*      rowstart = (int*)alloc((size_t)N * 4);
    int*      cursor   = (int*)alloc((size_t)N * 4);
    int*      partials = (int*)alloc((size_t)nb * 4);
    ushort_t* xlh      = (ushort_t*)alloc((size_t)N * 128 * 2);  // fp16 gather table
    ushort_t* xrh      = (ushort_t*)alloc((size_t)N * 128 * 2);  // fp16 target table
    ushort_t* Ah       = (ushort_t*)alloc((size_t)N * 128 * 2);
    ushort_t* Al       = (ushort_t*)alloc((size_t)N * 128 * 2);

    const int rowBlocks  = (N + 127) / 128;     // 391
    const int nodeBlocks = (N + 1) / 2;         // 2 waves/block (128 thr)
    const int edgeBlocks = (Et + 255) / 256;

    // ---- CSR by dst (once; reused by all layers) ----
    hipMemsetAsync(deg, 0, (size_t)N * 4, stream);
    build_edges_hist<<<edgeBlocks, 256, 0, stream>>>(ei, E, N, src, dst, deg);
    scan1<<<nb, 256, 0, stream>>>(deg, N, rowstart, partials);
    scan23<<<nb, 256, 0, stream>>>(rowstart, partials, nb, N, cursor);
    scatter_csr<<<edgeBlocks, 256, 0, stream>>>(src, dst, Et, cursor, csr_src);

    // ---- layer 1: 128 -> 4x32, concat, ELU (A converted inline from f32) ----
    gemm_mfma<128, true><<<dim3(rowBlocks, 4), 256, 0, stream>>>(
        nullptr, nullptr, x, Wl1, Wr1, xlh, xrh, N);
    node_attn<4, 32, true, 1><<<nodeBlocks, 128, 0, stream>>>(
        xlh, xrh, a1, b1, rowstart, deg, csr_src, N, nullptr, Ah, Al);

    // ---- layer 2: 128 -> 4x32, concat, ELU ----
    gemm_mfma<128, false><<<dim3(rowBlocks, 4), 256, 0, stream>>>(
        Ah, Al, nullptr, Wl2, Wr2, xlh, xrh, N);
    node_attn<4, 32, true, 1><<<nodeBlocks, 128, 0, stream>>>(
        xlh, xrh, a2, b2, rowstart, deg, csr_src, N, nullptr, Ah, Al);

    // ---- layer 3: 128 -> 64, heads=1, concat=False ----
    float* out = (float*)d_out;
    gemm_mfma<64, false><<<dim3(rowBlocks, 2), 256, 0, stream>>>(
        Ah, Al, nullptr, Wl3, Wr3, xlh, xrh, N);
    node_attn<1, 64, false, 0><<<nodeBlocks, 128, 0, stream>>>(
        xlh, xrh, a3, b3, rowstart, deg, csr_src, N, out, nullptr, nullptr);
}